// Round 8
// baseline (56.267 us; speedup 1.0000x reference)
//
#include <hip/hip_runtime.h>
#include <hip/hip_bf16.h>

#define T_TOTAL 200000

typedef float v4f __attribute__((ext_vector_type(4)));

// Parameter block layout (floats), phases in REVOLUTIONS, +0.25-shifted so
// sin(theta) = cos(2*pi*(fract(rev)-0.5)) (even poly, no sign fixup):
// [0..79]      layer0 quads per n<20 at 4n: {ww0', ph0'+0.25, C0=2cos(w*64d), A0}
// [80..1999]   layer1: per n<20, 96-float block at 80+96n:
//              [+m]=ww1'  [+32+m]=ph1'+0.25  [+64+m]=C1, m<32 (pads m>=25:
//              ww=0, ph=0.25 -> sin==0, C=2)
// [2000..4399] layer2: per n<25, 96-float block at 2000+96n (pads m>=30)
// [4400..4495] layer3: [+k]=ww3' [+32+k]=ph3'+0.25 [+64+k]=C3, k<32 (pads>=30)
// Loop prefetch overreads one block past the end of layers 1/2; those reads
// land in the next layer's block (in-bounds, values unused).
__device__ float g_P[4496];

// sin(2*pi*rev) via even poly: cos(2*pi*h), h = fract(rev)-0.5. |err| ~= 4e-5.
__device__ __forceinline__ float sinp(float rev) {
    float g = __builtin_amdgcn_fractf(rev);
    float h = g - 0.5f;
    float u = h * h;
    float p = fmaf(45.621248f, u, -82.391040f);
    p = fmaf(p, u, 64.671616f);
    p = fmaf(p, u, -19.730960f);
    p = fmaf(p, u, 0.9999618f);
    return p;
}

__global__ void prep_kernel(
    const float* __restrict__ A0,
    const float* __restrict__ w0, const float* __restrict__ phi0,
    const float* __restrict__ wc0, const float* __restrict__ phic0,
    const float* __restrict__ w1, const float* __restrict__ phi1,
    const float* __restrict__ wc1, const float* __restrict__ phic1,
    const float* __restrict__ w2, const float* __restrict__ phi2,
    const float* __restrict__ wc2, const float* __restrict__ phic2,
    const float* __restrict__ w3, const float* __restrict__ phi3,
    const float* __restrict__ wc3, const float* __restrict__ phic3)
{
    const int tid = blockIdx.x * blockDim.x + threadIdx.x;
    const int stride = blockDim.x * gridDim.x;

    const double I2PI = 0.15915494309189535;
    const double D64  = 64.0 * 999.0 / 199999.0;   // tv-step between j's

    const double ws0 = fmax((double)wc0[0], 0.0), ps0 = fmax((double)phic0[0], 0.0);
    const double ws1 = fmax((double)wc1[0], 0.0), ps1 = fmax((double)phic1[0], 0.0);
    const double ws2 = fmax((double)wc2[0], 0.0), ps2 = fmax((double)phic2[0], 0.0);
    const double ws3 = fmax((double)wc3[0], 0.0), ps3 = fmax((double)phic3[0], 0.0);

    for (int n = tid; n < 20; n += stride) {
        double wr = fmax((double)w0[n], 0.0) + ws0;
        g_P[4 * n]     = (float)(wr * I2PI);
        g_P[4 * n + 1] = (float)((fmax((double)phi0[n], 0.0) + ps0) * I2PI + 0.25);
        g_P[4 * n + 2] = (float)(2.0 * cos(wr * D64));
        g_P[4 * n + 3] = A0[n];
    }
    for (int k = tid; k < 20 * 32; k += stride) {
        const int n = k >> 5, m = k & 31;
        float wwf = 0.0f, phf = 0.25f, cf = 2.0f;
        if (m < 25) {
            const int s = m * 20 + n;
            double wr = fmax((double)w1[s], 0.0) + ws1;
            wwf = (float)(wr * I2PI);
            phf = (float)((fmax((double)phi1[s], 0.0) + ps1) * I2PI + 0.25);
            cf  = (float)(2.0 * cos(wr * D64));
        }
        g_P[80 + 96 * n + m]      = wwf;
        g_P[80 + 96 * n + 32 + m] = phf;
        g_P[80 + 96 * n + 64 + m] = cf;
    }
    for (int k = tid; k < 25 * 32; k += stride) {
        const int n = k >> 5, m = k & 31;
        float wwf = 0.0f, phf = 0.25f, cf = 2.0f;
        if (m < 30) {
            const int s = m * 25 + n;
            double wr = fmax((double)w2[s], 0.0) + ws2;
            wwf = (float)(wr * I2PI);
            phf = (float)((fmax((double)phi2[s], 0.0) + ps2) * I2PI + 0.25);
            cf  = (float)(2.0 * cos(wr * D64));
        }
        g_P[2000 + 96 * n + m]      = wwf;
        g_P[2000 + 96 * n + 32 + m] = phf;
        g_P[2000 + 96 * n + 64 + m] = cf;
    }
    for (int k = tid; k < 32; k += stride) {
        float wwf = 0.0f, phf = 0.25f, cf = 2.0f;
        if (k < 30) {
            double wr = fmax((double)w3[k], 0.0) + ws3;
            wwf = (float)(wr * I2PI);
            phf = (float)((fmax((double)phi3[k], 0.0) + ps3) * I2PI + 0.25);
            cf  = (float)(2.0 * cos(wr * D64));
        }
        g_P[4400 + k]      = wwf;
        g_P[4400 + 32 + k] = phf;
        g_P[4400 + 64 + k] = cf;
    }
}

// Block = 512 threads = 8 waves covering 256 t-values: t = tb + lane + 64*j,
// j=0..3 per thread. Per (m,n): j=0,1 direct poly, j=2,3 via 1-fma Chebyshev
// recurrence x_{j+1} = C*x_j - x_{j-1}. Wave w owns m = 4w..4w+3 in layers
// 1-3. s0 is RECOMPUTED inline by every wave (no sh0, no first barrier):
// +9% ops buys LDS 50->34 KB, so with __launch_bounds__(512,8) all 782
// blocks are co-resident (4 blocks/CU capacity) -> zero scheduling tail.
// Both n-loops manually software-pipeline (1-deep) their wave-uniform
// s_load bursts and the ds_read of s1.
__launch_bounds__(512, 8)
__global__ void wave_main(float* __restrict__ out)
{
    __shared__ float sh1[26 * 256];   // s1[m][lane*4+j]; row 25 = prefetch pad
    __shared__ float shp[8 * 256];    // partials [w][j*64+lane]

    const int l = threadIdx.x & 63;
    const int w = __builtin_amdgcn_readfirstlane(threadIdx.x >> 6);
    const int tb = blockIdx.x * 256;
    const float STEP = 999.0f / 199999.0f;

    const float tv0 = fmaf((float)(tb + l), STEP, 1.0f);
    const float tv1 = fmaf((float)(tb + l + 64), STEP, 1.0f);

    // ---- layer 1 (with inline layer-0 recompute): wave w owns m = 4w+k ----
    float acc1[4][4] = {};
    float sum0[4] = {0.f, 0.f, 0.f, 0.f};
    {
        v4f qN  = *(const v4f*)&g_P[0];
        v4f wwN = *(const v4f*)&g_P[80 + 4 * w];
        v4f phN = *(const v4f*)&g_P[80 + 32 + 4 * w];
        v4f CN  = *(const v4f*)&g_P[80 + 64 + 4 * w];
#pragma clang loop unroll(disable)
        for (int n = 0; n < 20; ++n) {
            const v4f q = qN, ww4 = wwN, ph4 = phN, C4 = CN;
            // prefetch n+1 (overread at n=19 lands in layer2's block; unused)
            qN  = *(const v4f*)&g_P[4 * (n + 1)];
            const float* __restrict__ pn = &g_P[80 + 96 * (n + 1) + 4 * w];
            wwN = *(const v4f*)&pn[0];
            phN = *(const v4f*)&pn[32];
            CN  = *(const v4f*)&pn[64];

            // s0[n] at j=0..3 (Chebyshev over j)
            float s00 = q[3] * sinp(fmaf(q[0], tv0, q[1]));
            float s01 = q[3] * sinp(fmaf(q[0], tv1, q[1]));
            float s02 = fmaf(q[2], s01, -s00);
            float s03 = fmaf(q[2], s02, -s01);
            sum0[0] += s00; sum0[1] += s01; sum0[2] += s02; sum0[3] += s03;
#pragma unroll
            for (int k = 0; k < 4; ++k) {
                float x0 = sinp(fmaf(ww4[k], tv0, ph4[k]));
                float x1 = sinp(fmaf(ww4[k], tv1, ph4[k]));
                float x2 = fmaf(C4[k], x1, -x0);
                float x3 = fmaf(C4[k], x2, -x1);
                acc1[k][0] = fmaf(x0, s00, acc1[k][0]);
                acc1[k][1] = fmaf(x1, s01, acc1[k][1]);
                acc1[k][2] = fmaf(x2, s02, acc1[k][2]);
                acc1[k][3] = fmaf(x3, s03, acc1[k][3]);
            }
        }
    }
#pragma unroll
    for (int k = 0; k < 4; ++k) {
        if (4 * w + k < 25) {          // wave-uniform guard
            v4f v;
#pragma unroll
            for (int j = 0; j < 4; ++j) v[j] = fmaf(0.5f, acc1[k][j], 0.5f * sum0[j]);
            *(v4f*)&sh1[(4 * w + k) * 256 + l * 4] = v;
        }
    }
    __syncthreads();

    // ---- layer 2: wave w owns m = 4w+k; s2 stays in regs ----
    float acc2[4][4] = {};
    float sum1[4] = {0.f, 0.f, 0.f, 0.f};
    {
        v4f s1N = *(const v4f*)&sh1[l * 4];
        v4f wwN = *(const v4f*)&g_P[2000 + 4 * w];
        v4f phN = *(const v4f*)&g_P[2000 + 32 + 4 * w];
        v4f CN  = *(const v4f*)&g_P[2000 + 64 + 4 * w];
#pragma clang loop unroll(disable)
        for (int n = 0; n < 25; ++n) {
            const v4f s1 = s1N, ww4 = wwN, ph4 = phN, C4 = CN;
            // prefetch n+1 (param overread at n=24 lands in layer3's block)
            s1N = *(const v4f*)&sh1[(n + 1) * 256 + l * 4];
            const float* __restrict__ pn = &g_P[2000 + 96 * (n + 1) + 4 * w];
            wwN = *(const v4f*)&pn[0];
            phN = *(const v4f*)&pn[32];
            CN  = *(const v4f*)&pn[64];

            sum1[0] += s1[0]; sum1[1] += s1[1]; sum1[2] += s1[2]; sum1[3] += s1[3];
#pragma unroll
            for (int k = 0; k < 4; ++k) {
                float x0 = sinp(fmaf(ww4[k], tv0, ph4[k]));
                float x1 = sinp(fmaf(ww4[k], tv1, ph4[k]));
                float x2 = fmaf(C4[k], x1, -x0);
                float x3 = fmaf(C4[k], x2, -x1);
                acc2[k][0] = fmaf(x0, s1[0], acc2[k][0]);
                acc2[k][1] = fmaf(x1, s1[1], acc2[k][1]);
                acc2[k][2] = fmaf(x2, s1[2], acc2[k][2]);
                acc2[k][3] = fmaf(x3, s1[3], acc2[k][3]);
            }
        }
    }
    float s2r[4][4];
#pragma unroll
    for (int k = 0; k < 4; ++k)
#pragma unroll
        for (int j = 0; j < 4; ++j)
            s2r[k][j] = fmaf(0.5f, acc2[k][j], 0.5f * sum1[j]);

    // ---- layer 3: per-wave partial over its own m-slice (registers) ----
    float pw[4] = {0.f, 0.f, 0.f, 0.f};
    {
        const float* __restrict__ pb = &g_P[4400 + 4 * w];
#pragma unroll
        for (int k = 0; k < 4; ++k) {
            if (4 * w + k < 30) {      // wave-uniform guard (skips pads)
                const float ww = pb[k], ph = pb[32 + k], C = pb[64 + k];
                float x0 = sinp(fmaf(ww, tv0, ph));
                float x1 = sinp(fmaf(ww, tv1, ph));
                float x2 = fmaf(C, x1, -x0);
                float x3 = fmaf(C, x2, -x1);
                pw[0] = fmaf(fmaf(0.5f, x0, 0.5f), s2r[k][0], pw[0]);
                pw[1] = fmaf(fmaf(0.5f, x1, 0.5f), s2r[k][1], pw[1]);
                pw[2] = fmaf(fmaf(0.5f, x2, 0.5f), s2r[k][2], pw[2]);
                pw[3] = fmaf(fmaf(0.5f, x3, 0.5f), s2r[k][3], pw[3]);
            }
        }
    }
#pragma unroll
    for (int j = 0; j < 4; ++j)
        shp[w * 256 + j * 64 + l] = pw[j];   // [w][j][lane]: conflict-free
    __syncthreads();

    // cross-wave reduce: wave w (w<4) handles j == w
    if (w < 4) {
        float r = 0.0f;
#pragma unroll
        for (int w2 = 0; w2 < 8; ++w2)
            r += shp[w2 * 256 + w * 64 + l];
        const int tt = tb + l + 64 * w;
        if (tt < T_TOTAL) out[tt] = r;
    }
}

extern "C" void kernel_launch(void* const* d_in, const int* in_sizes, int n_in,
                              void* d_out, int out_size, void* d_ws, size_t ws_size,
                              hipStream_t stream) {
    (void)in_sizes; (void)n_in; (void)d_ws; (void)ws_size; (void)out_size;
    const float* A0    = (const float*)d_in[1];
    const float* w0    = (const float*)d_in[2];
    const float* phi0  = (const float*)d_in[3];
    const float* wc0   = (const float*)d_in[4];
    const float* phic0 = (const float*)d_in[5];
    const float* w1    = (const float*)d_in[6];
    const float* phi1  = (const float*)d_in[7];
    const float* wc1   = (const float*)d_in[8];
    const float* phic1 = (const float*)d_in[9];
    const float* w2    = (const float*)d_in[10];
    const float* phi2  = (const float*)d_in[11];
    const float* wc2   = (const float*)d_in[12];
    const float* phic2 = (const float*)d_in[13];
    const float* w3    = (const float*)d_in[14];
    const float* phi3  = (const float*)d_in[15];
    const float* wc3   = (const float*)d_in[16];
    const float* phic3 = (const float*)d_in[17];

    float* out = (float*)d_out;

    hipLaunchKernelGGL(prep_kernel, dim3(6), dim3(256), 0, stream,
                       A0, w0, phi0, wc0, phic0,
                       w1, phi1, wc1, phic1,
                       w2, phi2, wc2, phic2,
                       w3, phi3, wc3, phic3);

    const int grid = (T_TOTAL + 255) / 256;   // 782
    hipLaunchKernelGGL(wave_main, dim3(grid), dim3(512), 0, stream, out);
}